// Round 2
// baseline (450.662 us; speedup 1.0000x reference)
//
#include <hip/hip_runtime.h>
#include <math.h>

// CorollaryResonanceBank — fused single-kernel implementation.
//
// Shapes: B=256, C=64, T=2048, R=16, TIME_BINS=128, WIN=T/TIME_BINS=16.
// Memory-bound: reads 384 MiB once (transmit 128 MiB + receive 256 MiB),
// writes 16 KB. Roofline floor ~64 us at 6.3 TB/s achievable.
//
// One block per batch element b (grid=256 -> 1 block/CU, 8 waves/CU);
// 512 threads; each thread owns 4 consecutive t (float4 loads, 16 B/lane).
// Phases:
//   1) c-reduction: per-t sums (transmit, left, right, elevation), unroll 8
//   2) traces -> 16-wide window means (4-lane shfl reduce) into LDS (3x128 f32)
//   3) block max-abs -> scale
//   4) lanes 0..15: 128-step resonate-and-fire scan per r, write (B,R) means.

#define NB 256
#define NC 64
#define NT 2048
#define NR 16
#define NTB 128
#define NWIN 16

__global__ __launch_bounds__(512) void crb_kernel(
    const float* __restrict__ transmit,   // (B,C,T)
    const float* __restrict__ receive,    // (B,2,C,T)
    const float* __restrict__ conv_w,     // (R,3)
    const float* __restrict__ conv_b,     // (R,)
    const float* __restrict__ frequency,  // (R,)
    const float* __restrict__ decay,      // (R,)
    const float* __restrict__ threshold,  // (R,)
    const float* __restrict__ tw,         // scalar
    const float* __restrict__ rw,         // scalar
    float* __restrict__ out)              // (B,R)
{
    const int b   = blockIdx.x;
    const int tid = threadIdx.x;
    const int t0  = tid * 4;              // 4 consecutive t per thread

    __shared__ float sdw[NTB];            // pooled signed_distance windows
    __shared__ float azw[NTB];            // pooled azimuth windows
    __shared__ float elw[NTB];            // pooled elevation windows
    __shared__ float red[8];              // per-wave max partials
    __shared__ float s_scale;

    // ---------- Phase 1: channel reduction (the 384 MiB stream) ----------
    float ts0=0.f, ts1=0.f, ts2=0.f, ts3=0.f;   // transmit sum
    float ls0=0.f, ls1=0.f, ls2=0.f, ls3=0.f;   // left sum
    float rs0=0.f, rs1=0.f, rs2=0.f, rs3=0.f;   // right sum
    float es0=0.f, es1=0.f, es2=0.f, es3=0.f;   // elevation sum

    const float4* tp = reinterpret_cast<const float4*>(
        transmit + (size_t)b * NC * NT + t0);
    const float4* lp = reinterpret_cast<const float4*>(
        receive + ((size_t)b * 2 + 0) * NC * NT + t0);
    const float4* rp = reinterpret_cast<const float4*>(
        receive + ((size_t)b * 2 + 1) * NC * NT + t0);
    const int row = NT / 4;               // float4 stride between c rows

    #pragma unroll 8
    for (int c = 0; c < NC; ++c) {
        const float ch = fmaf((float)c, 2.0f / 63.0f, -1.0f); // linspace(-1,1,64)
        const float4 tv = tp[c * row];
        const float4 lv = lp[c * row];
        const float4 rv = rp[c * row];
        ts0 += tv.x; ts1 += tv.y; ts2 += tv.z; ts3 += tv.w;
        ls0 += lv.x; ls1 += lv.y; ls2 += lv.z; ls3 += lv.w;
        rs0 += rv.x; rs1 += rv.y; rs2 += rv.z; rs3 += rv.w;
        es0 = fmaf(lv.x + rv.x, ch, es0);
        es1 = fmaf(lv.y + rv.y, ch, es1);
        es2 = fmaf(lv.z + rv.z, ch, es2);
        es3 = fmaf(lv.w + rv.w, ch, es3);
    }

    // ---------- Phase 2: traces -> window means ----------
    const float sp_tw = log1pf(expf(tw[0]));   // softplus(transmit_weight)
    const float sp_rw = log1pf(expf(rw[0]));   // softplus(receive_weight)

    // signed_distance = sp_rw * 0.5*(l+r) - sp_tw * t ; azimuth = l-r ; elev = e
    float sd4, az4, el4;
    {
        const float sdv0 = sp_rw * 0.5f * (ls0 + rs0) - sp_tw * ts0;
        const float sdv1 = sp_rw * 0.5f * (ls1 + rs1) - sp_tw * ts1;
        const float sdv2 = sp_rw * 0.5f * (ls2 + rs2) - sp_tw * ts2;
        const float sdv3 = sp_rw * 0.5f * (ls3 + rs3) - sp_tw * ts3;
        sd4 = ((sdv0 + sdv1) + (sdv2 + sdv3));
        az4 = ((ls0 - rs0) + (ls1 - rs1)) + ((ls2 - rs2) + (ls3 - rs3));
        el4 = (es0 + es1) + (es2 + es3);
    }
    // 16-wide window = 4 threads x 4 t each; reduce across the 4-lane group
    sd4 += __shfl_xor(sd4, 1); sd4 += __shfl_xor(sd4, 2);
    az4 += __shfl_xor(az4, 1); az4 += __shfl_xor(az4, 2);
    el4 += __shfl_xor(el4, 1); el4 += __shfl_xor(el4, 2);

    if ((tid & 3) == 0) {
        const int w = tid >> 2;           // window index 0..127
        sdw[w] = sd4 * (1.0f / NWIN);
        azw[w] = az4 * (1.0f / NWIN);
        elw[w] = el4 * (1.0f / NWIN);
    }
    __syncthreads();

    // ---------- Phase 3: scale = max(|traces|, 1.0) over 3*128 values ----------
    float m = 0.f;
    if (tid < 3 * NTB) {
        const float v = (tid < NTB) ? sdw[tid]
                      : (tid < 2 * NTB) ? azw[tid - NTB]
                      : elw[tid - 2 * NTB];
        m = fabsf(v);
    }
    #pragma unroll
    for (int off = 32; off >= 1; off >>= 1)
        m = fmaxf(m, __shfl_xor(m, off));
    if ((tid & 63) == 0) red[tid >> 6] = m;
    __syncthreads();
    if (tid == 0) {
        float mm = red[0];
        #pragma unroll
        for (int i = 1; i < 8; ++i) mm = fmaxf(mm, red[i]);
        s_scale = fmaxf(mm, 1.0f);
    }
    __syncthreads();

    // ---------- Phase 4: resonate-and-fire scan (lanes 0..R-1) ----------
    if (tid < NR) {
        const int r = tid;
        const float inv_scale = 1.0f / s_scale;
        const float w0 = conv_w[r * 3 + 0];
        const float w1 = conv_w[r * 3 + 1];
        const float w2 = conv_w[r * 3 + 2];
        const float bias = conv_b[r];
        const float fr = 0.02f + 0.18f / (1.0f + expf(-frequency[r]));
        const float dc = 0.80f + 0.18f / (1.0f + expf(-decay[r]));
        const float th = 0.35f + 0.75f / (1.0f + expf(-threshold[r]));

        float st = 0.f, vel = 0.f, cnt = 0.f;
        for (int t = 0; t < NTB; ++t) {
            const float cur =
                (sdw[t] * w0 + azw[t] * w1 + elw[t] * w2) * inv_scale + bias;
            vel = dc * vel + cur - fr * st;
            st  = st + fr * vel;
            const float sp = ((st - th) > 0.0f) ? 1.0f : 0.0f;
            st -= sp * th;
            cnt += sp;
        }
        out[(size_t)b * NR + r] = cnt * (1.0f / NTB);
    }
}

extern "C" void kernel_launch(void* const* d_in, const int* in_sizes, int n_in,
                              void* d_out, int out_size, void* d_ws, size_t ws_size,
                              hipStream_t stream) {
    const float* transmit  = (const float*)d_in[0];  // (B,C,T)
    const float* receive   = (const float*)d_in[1];  // (B,2,C,T)
    const float* conv_w    = (const float*)d_in[2];  // (R,3)
    const float* conv_b    = (const float*)d_in[3];  // (R,)
    const float* frequency = (const float*)d_in[4];  // (R,)
    const float* decay     = (const float*)d_in[5];  // (R,)
    const float* threshold = (const float*)d_in[6];  // (R,)
    const float* tw        = (const float*)d_in[7];  // scalar
    const float* rw        = (const float*)d_in[8];  // scalar
    float* out = (float*)d_out;                      // (B,R) f32

    crb_kernel<<<NB, 512, 0, stream>>>(transmit, receive, conv_w, conv_b,
                                       frequency, decay, threshold, tw, rw, out);
}